// Round 18
// baseline (188.179 us; speedup 1.0000x reference)
//
#include <hip/hip_runtime.h>
#include <stdint.h>
#include <math.h>

#define NN 8192
#define DD 512
#define KSEL 4096
#define NW 128   // u64 words per full row bitset
#define DEGP 192 // padded neighbor-list length

typedef float f32x4 __attribute__((ext_vector_type(4)));

// pi-8192 (full bitsets R): column j -> word ((j>>8)<<2)|(j&3), bit (j>>2)&63
// pi-4096 (Rsel/T_bits, 64 words): position c=it*256+l*4+e -> word it*4+e, bit l

// ------------- Kernel 1: fused pack (blocks 0..2047) + scores (2048..4095) --
__global__ __launch_bounds__(256) void k_pack_scores(const float* __restrict__ g,
                                                     const float* __restrict__ h,
                                                     const float* __restrict__ W,
                                                     const float* __restrict__ b,
                                                     uint64_t* __restrict__ R,
                                                     double* __restrict__ w64,
                                                     float* __restrict__ val) {
    int wave = threadIdx.x >> 6;
    int lane = threadIdx.x & 63;
    if (blockIdx.x < 2048) {
        int row = blockIdx.x * 4 + wave;
        const f32x4* gr = (const f32x4*)(g + (size_t)row * NN);
        uint64_t* Rr = R + (size_t)row * NW;
        #pragma unroll 4
        for (int gi = 0; gi < 32; ++gi) {
            f32x4 v = __builtin_nontemporal_load(&gr[gi * 64 + lane]);
            int n = (v.x != 0.0f) | ((v.y != 0.0f) << 1)
                  | ((v.z != 0.0f) << 2) | ((v.w != 0.0f) << 3);
            uint64_t b0 = __ballot(n & 1);
            uint64_t b1 = __ballot(n & 2);
            uint64_t b2 = __ballot(n & 4);
            uint64_t b3 = __ballot(n & 8);
            if (lane == 0) {
                Rr[gi * 4 + 0] = b0;
                Rr[gi * 4 + 1] = b1;
                Rr[gi * 4 + 2] = b2;
                Rr[gi * 4 + 3] = b3;
            }
        }
    } else {
        int row = (blockIdx.x - 2048) * 4 + wave;
        const float4* h4 = (const float4*)(h + (size_t)row * DD);
        const float4* w4 = (const float4*)W;
        float4 a0 = h4[lane * 2], a1 = h4[lane * 2 + 1];
        float4 b0 = w4[lane * 2], b1 = w4[lane * 2 + 1];
        double p = (double)a0.x * (double)b0.x + (double)a0.y * (double)b0.y
                 + (double)a0.z * (double)b0.z + (double)a0.w * (double)b0.w
                 + (double)a1.x * (double)b1.x + (double)a1.y * (double)b1.y
                 + (double)a1.z * (double)b1.z + (double)a1.w * (double)b1.w;
        #pragma unroll
        for (int off = 32; off >= 1; off >>= 1) p += __shfl_xor(p, off);
        if (lane == 0) {
            double wgt = p + (double)b[0];
            w64[row] = wgt;
            val[row] = (float)(1.0 / (1.0 + exp(-wgt)));
        }
    }
}

// ------------- Kernel 2: top-K rank + inverse-rank map + fused new_h --------
__global__ __launch_bounds__(1024) void k_topk(const double* __restrict__ w64,
                                               const float* __restrict__ val,
                                               const float* __restrict__ h,
                                               int* __restrict__ idx_i,
                                               int* __restrict__ inv,
                                               float* __restrict__ idx_f,
                                               float* __restrict__ out_h) {
    __shared__ double s[NN];  // 64 KB
    for (int t = threadIdx.x; t < NN; t += 1024) s[t] = w64[t];
    __syncthreads();

    int wave = threadIdx.x >> 6;
    int lane = threadIdx.x & 63;
    int i = blockIdx.x * 16 + wave;
    double wi = s[i];
    int rank = 0;
    #pragma unroll 4
    for (int j = lane; j < NN; j += 64) {
        double wj = s[j];
        rank += (wj > wi) || (wj == wi && j < i);
    }
    #pragma unroll
    for (int off = 32; off >= 1; off >>= 1) rank += __shfl_xor(rank, off);

    if (lane == 0) inv[i] = rank;
    if (rank < KSEL) {
        float v = val[i];
        const f32x4* src = (const f32x4*)(h + (size_t)i * DD);
        f32x4* dst = (f32x4*)(out_h + (size_t)rank * DD);
        #pragma unroll
        for (int t = 0; t < 2; ++t) {
            f32x4 x = src[lane + t * 64];
            x *= v;
            __builtin_nontemporal_store(x, &dst[lane + t * 64]);
        }
        if (lane == 0) {
            idx_i[rank] = i;
            idx_f[rank] = (float)i;
        }
    }
}

// ------------- Kernel 3: fused Rsel + CSR extraction (one pass over R) ------
__global__ __launch_bounds__(512) void k_selnbr(const uint64_t* __restrict__ R,
                                                const int* __restrict__ idx_i,
                                                const int* __restrict__ inv,
                                                uint64_t* __restrict__ Rsel,
                                                uint16_t* __restrict__ nbr_g,
                                                int* __restrict__ ndeg) {
    __shared__ uint16_t idx_s[KSEL];   // 8 KB
    __shared__ uint64_t rb[8][NW];     // 8 KB
    for (int t = threadIdx.x; t < KSEL; t += 512) idx_s[t] = (uint16_t)idx_i[t];

    int wave = threadIdx.x >> 6;
    int lane = threadIdx.x & 63;
    int k = blockIdx.x * 8 + wave;
    const ulonglong2* R2 = (const ulonglong2*)R;
    ulonglong2 own = R2[(size_t)k * 64 + lane];
    rb[wave][2 * lane]     = own.x;
    rb[wave][2 * lane + 1] = own.y;
    __syncthreads();

    const uint64_t* rw = rb[wave];
    uint64_t v = 0;
    #pragma unroll
    for (int it = 0; it < 16; ++it) {
        ushort4 j4 = *(const ushort4*)&idx_s[it * 256 + lane * 4];
        int wx = ((j4.x >> 8) << 2) | (j4.x & 3);
        int wy = ((j4.y >> 8) << 2) | (j4.y & 3);
        int wz = ((j4.z >> 8) << 2) | (j4.z & 3);
        int ww = ((j4.w >> 8) << 2) | (j4.w & 3);
        int n = (int)((rw[wx] >> ((j4.x >> 2) & 63)) & 1ull)
              | ((int)((rw[wy] >> ((j4.y >> 2) & 63)) & 1ull) << 1)
              | ((int)((rw[wz] >> ((j4.z >> 2) & 63)) & 1ull) << 2)
              | ((int)((rw[ww] >> ((j4.w >> 2) & 63)) & 1ull) << 3);
        uint64_t b0 = __ballot(n & 1);
        uint64_t b1 = __ballot(n & 2);
        uint64_t b2 = __ballot(n & 4);
        uint64_t b3 = __ballot(n & 8);
        if ((lane >> 2) == it) {
            int e = lane & 3;
            v = (e == 0) ? b0 : (e == 1) ? b1 : (e == 2) ? b2 : b3;
        }
    }
    Rsel[(size_t)k * 64 + lane] = v;

    int rank = inv[k];
    if (rank < KSEL) {
        uint64_t m0 = own.x, m1 = own.y;
        int mycnt = __popcll(m0) + __popcll(m1);
        int w0 = lane * 2, w1 = lane * 2 + 1;
        int myfirst = 0;
        if (m0)      { int l = __builtin_ctzll(m0); myfirst = ((w0 >> 2) << 8) + (l << 2) + (w0 & 3); }
        else if (m1) { int l = __builtin_ctzll(m1); myfirst = ((w1 >> 2) << 8) + (l << 2) + (w1 & 3); }
        unsigned long long has = __ballot(mycnt > 0);
        int firstlane = has ? __builtin_ctzll(has) : 0;
        int e0 = __shfl(myfirst, firstlane);

        int incl = mycnt;
        #pragma unroll
        for (int d = 1; d < 64; d <<= 1) {
            int t = __shfl_up(incl, d);
            if (lane >= d) incl += t;
        }
        int pos = incl - mycnt;
        int total = __shfl(incl, 63);

        uint16_t* dst = nbr_g + (size_t)rank * DEGP;
        while (m0) {
            int l = __builtin_ctzll(m0); m0 &= m0 - 1;
            if (pos < DEGP) dst[pos] = (uint16_t)(((w0 >> 2) << 8) + (l << 2) + (w0 & 3));
            ++pos;
        }
        while (m1) {
            int l = __builtin_ctzll(m1); m1 &= m1 - 1;
            if (pos < DEGP) dst[pos] = (uint16_t)(((w1 >> 2) << 8) + (l << 2) + (w1 & 3));
            ++pos;
        }
        for (int p = total + lane; p < DEGP; p += 64) dst[p] = (uint16_t)e0;
        if (lane == 0) ndeg[rank] = (total < DEGP) ? total : DEGP;
    }
}

// ------------- Kernel 4: XCD-sliced OR -> T_bits ----------------------------
// grid = 1024 rowgroups x 8 slices; slice = blockIdx&7 -> XCD (round-robin),
// so each XCD's L2 only holds words [8s,8s+8) of Rsel = 512 KB (resident).
// Wave w handles row rg*4+w; one wave-load = 8 neighbors x 8 words (64B each).
__global__ __launch_bounds__(256) void k_orgx(const uint64_t* __restrict__ Rsel,
                                              const uint16_t* __restrict__ nbr_g,
                                              const int* __restrict__ ndeg,
                                              uint64_t* __restrict__ T_bits) {
    __shared__ uint32_t nbs[4][96];   // per-wave CSR row (384 B each)
    int slice = blockIdx.x & 7;
    int rg    = blockIdx.x >> 3;
    int wave  = threadIdx.x >> 6;
    int lane  = threadIdx.x & 63;
    int r = rg * 4 + wave;

    const uint32_t* src = (const uint32_t*)(nbr_g + (size_t)r * DEGP);
    if (lane < 96) nbs[wave][lane] = src[lane];   // wave-local, no block sync needed
    int deg = ndeg[r];
    int iters = (deg + 7) >> 3;                   // e0-padded: full batches safe

    int word = lane & 7;
    int grp  = lane >> 3;
    const uint64_t* base = Rsel + (size_t)slice * 8 + word;
    const uint16_t* nb16 = (const uint16_t*)nbs[wave];
    uint64_t acc = 0;
    for (int it = 0; it < iters; ++it) {
        int n = nb16[it * 8 + grp];               // LDS broadcast within group
        acc |= base[(size_t)n * 64];              // 64B per neighbor slice
    }
    #pragma unroll
    for (int off = 8; off < 64; off <<= 1) acc |= __shfl_xor(acc, off);
    if (lane < 8) T_bits[(size_t)r * 64 + slice * 8 + lane] = acc;
}

// ------------- Kernel 5: expand T_bits row -> normalized float row ----------
// pi-4096 decode (FIXED store indexing): thread t writes columns [16t,16t+16).
__global__ __launch_bounds__(256) void k_wrg(const uint64_t* __restrict__ T_bits,
                                             float* __restrict__ out_g) {
    __shared__ uint64_t C[64];
    __shared__ float rcpS;
    int r = blockIdx.x;
    int t = threadIdx.x;
    if (t < 64) {
        uint64_t w = T_bits[(size_t)r * 64 + t];
        C[t] = w;
        int c = __popcll(w);
        #pragma unroll
        for (int off = 32; off >= 1; off >>= 1) c += __shfl_xor(c, off);
        if (t == 0) rcpS = 1.0f / (float)c;
    }
    __syncthreads();
    float recip = rcpS;

    int it = t >> 4;                 // column block of 256
    int lbase = (4 * t) & 63;        // l for q=0
    uint64_t wA = C[it * 4 + 0], wB = C[it * 4 + 1];
    uint64_t wC = C[it * 4 + 2], wD = C[it * 4 + 3];
    f32x4* dst = (f32x4*)(out_g + (size_t)r * KSEL);
    #pragma unroll
    for (int q = 0; q < 4; ++q) {
        int l = lbase + q;
        f32x4 v;
        v.x = ((wA >> l) & 1ull) ? recip : 0.0f;
        v.y = ((wB >> l) & 1ull) ? recip : 0.0f;
        v.z = ((wC >> l) & 1ull) ? recip : 0.0f;
        v.w = ((wD >> l) & 1ull) ? recip : 0.0f;
        __builtin_nontemporal_store(v, &dst[t * 4 + q]);
    }
}

extern "C" void kernel_launch(void* const* d_in, const int* in_sizes, int n_in,
                              void* d_out, int out_size, void* d_ws, size_t ws_size,
                              hipStream_t stream) {
    const float* g = (const float*)d_in[0];
    const float* h = (const float*)d_in[1];
    const float* W = (const float*)d_in[2];
    const float* b = (const float*)d_in[3];

    float* out_g   = (float*)d_out;                // K*K
    float* out_h   = out_g + (size_t)KSEL * KSEL;  // K*D
    float* out_idx = out_h + (size_t)KSEL * DD;    // K

    char* ws = (char*)d_ws;
    double*   w64    = (double*)ws;                           // 64 KB
    float*    val    = (float*)(ws + 65536);                  // 32 KB
    int*      idx_i  = (int*)(ws + 98304);                    // 16 KB
    int*      ndeg   = (int*)(ws + 114688);                   // 16 KB
    int*      inv    = (int*)(ws + 131072);                   // 32 KB
    uint64_t* R      = (uint64_t*)(ws + 163840);              // 8 MB
    uint64_t* Rsel   = (uint64_t*)(ws + 163840 + 8388608);    // 4 MB
    uint16_t* nbr_g  = (uint16_t*)(ws + 163840 + 12582912);   // 1.5 MB
    uint64_t* T_bits = (uint64_t*)(ws + 163840 + 14155776);   // 2 MB

    k_pack_scores<<<4096, 256, 0, stream>>>(g, h, W, b, R, w64, val);
    k_topk<<<NN / 16, 1024, 0, stream>>>(w64, val, h, idx_i, inv, out_idx, out_h);
    k_selnbr<<<NN / 8, 512, 0, stream>>>(R, idx_i, inv, Rsel, nbr_g, ndeg);
    k_orgx<<<8192, 256, 0, stream>>>(Rsel, nbr_g, ndeg, T_bits);
    k_wrg<<<KSEL, 256, 0, stream>>>(T_bits, out_g);
}

// Round 19
// 104.067 us; speedup vs baseline: 1.8083x; 1.8083x over previous
//
#include <hip/hip_runtime.h>
#include <stdint.h>
#include <math.h>

#define NN 8192
#define DD 512
#define KSEL 4096
#define NW 128   // u64 words per full row bitset
#define DEGP 192 // padded neighbor-list length (deg ~ Binom(8192,.01): max ~125)

typedef float f32x4 __attribute__((ext_vector_type(4)));

// pi-8192 (full bitsets R): column j -> word ((j>>8)<<2)|(j&3), bit (j>>2)&63
// pi-4096 (selected bitsets Rsel, 64 words): position c=it*256+l*4+e -> word it*4+e, bit l

// ------------- Kernel 1: fused pack (blocks 0..2047) + scores (2048..4095) --
__global__ __launch_bounds__(256) void k_pack_scores(const float* __restrict__ g,
                                                     const float* __restrict__ h,
                                                     const float* __restrict__ W,
                                                     const float* __restrict__ b,
                                                     uint64_t* __restrict__ R,
                                                     double* __restrict__ w64,
                                                     float* __restrict__ val) {
    int wave = threadIdx.x >> 6;
    int lane = threadIdx.x & 63;
    if (blockIdx.x < 2048) {
        int row = blockIdx.x * 4 + wave;
        const f32x4* gr = (const f32x4*)(g + (size_t)row * NN);
        uint64_t* Rr = R + (size_t)row * NW;
        #pragma unroll 4
        for (int gi = 0; gi < 32; ++gi) {
            f32x4 v = __builtin_nontemporal_load(&gr[gi * 64 + lane]);
            int n = (v.x != 0.0f) | ((v.y != 0.0f) << 1)
                  | ((v.z != 0.0f) << 2) | ((v.w != 0.0f) << 3);
            uint64_t b0 = __ballot(n & 1);
            uint64_t b1 = __ballot(n & 2);
            uint64_t b2 = __ballot(n & 4);
            uint64_t b3 = __ballot(n & 8);
            if (lane == 0) {
                Rr[gi * 4 + 0] = b0;
                Rr[gi * 4 + 1] = b1;
                Rr[gi * 4 + 2] = b2;
                Rr[gi * 4 + 3] = b3;
            }
        }
    } else {
        int row = (blockIdx.x - 2048) * 4 + wave;
        const float4* h4 = (const float4*)(h + (size_t)row * DD);
        const float4* w4 = (const float4*)W;
        float4 a0 = h4[lane * 2], a1 = h4[lane * 2 + 1];
        float4 b0 = w4[lane * 2], b1 = w4[lane * 2 + 1];
        double p = (double)a0.x * (double)b0.x + (double)a0.y * (double)b0.y
                 + (double)a0.z * (double)b0.z + (double)a0.w * (double)b0.w
                 + (double)a1.x * (double)b1.x + (double)a1.y * (double)b1.y
                 + (double)a1.z * (double)b1.z + (double)a1.w * (double)b1.w;
        #pragma unroll
        for (int off = 32; off >= 1; off >>= 1) p += __shfl_xor(p, off);
        if (lane == 0) {
            double wgt = p + (double)b[0];
            w64[row] = wgt;
            val[row] = (float)(1.0 / (1.0 + exp(-wgt)));
        }
    }
}

// ------------- Kernel 2: top-K rank on f64 keys + fused new_h row copy ------
__global__ __launch_bounds__(1024) void k_topk(const double* __restrict__ w64,
                                               const float* __restrict__ val,
                                               const float* __restrict__ h,
                                               int* __restrict__ idx_i,
                                               float* __restrict__ idx_f,
                                               float* __restrict__ out_h) {
    __shared__ double s[NN];  // 64 KB
    for (int t = threadIdx.x; t < NN; t += 1024) s[t] = w64[t];
    __syncthreads();

    int wave = threadIdx.x >> 6;
    int lane = threadIdx.x & 63;
    int i = blockIdx.x * 16 + wave;
    double wi = s[i];
    int rank = 0;
    #pragma unroll 4
    for (int j = lane; j < NN; j += 64) {
        double wj = s[j];
        rank += (wj > wi) || (wj == wi && j < i);
    }
    #pragma unroll
    for (int off = 32; off >= 1; off >>= 1) rank += __shfl_xor(rank, off);

    if (rank < KSEL) {
        float v = val[i];
        const f32x4* src = (const f32x4*)(h + (size_t)i * DD);
        f32x4* dst = (f32x4*)(out_h + (size_t)rank * DD);
        #pragma unroll
        for (int t = 0; t < 2; ++t) {
            f32x4 x = src[lane + t * 64];
            x *= v;
            __builtin_nontemporal_store(x, &dst[lane + t * 64]);
        }
        if (lane == 0) {
            idx_i[rank] = i;
            idx_f[rank] = (float)i;
        }
    }
}

// ------------- Kernel 3: Rsel[k] = selected-column bits of R[k] (pi-4096) ---
__global__ __launch_bounds__(512) void k_sel(const uint64_t* __restrict__ R,
                                             const int* __restrict__ idx_i,
                                             uint64_t* __restrict__ Rsel) {
    __shared__ uint16_t idx_s[KSEL];   // 8 KB
    __shared__ uint64_t rb[8][NW];     // 8 KB
    for (int t = threadIdx.x; t < KSEL; t += 512) idx_s[t] = (uint16_t)idx_i[t];

    int wave = threadIdx.x >> 6;
    int lane = threadIdx.x & 63;
    int row  = blockIdx.x * 8 + wave;
    const ulonglong2* R2 = (const ulonglong2*)R;
    ulonglong2 own = R2[(size_t)row * 64 + lane];
    rb[wave][2 * lane]     = own.x;
    rb[wave][2 * lane + 1] = own.y;
    __syncthreads();

    const uint64_t* rw = rb[wave];
    uint64_t v = 0;
    #pragma unroll
    for (int it = 0; it < 16; ++it) {
        ushort4 j4 = *(const ushort4*)&idx_s[it * 256 + lane * 4];
        int wx = ((j4.x >> 8) << 2) | (j4.x & 3);
        int wy = ((j4.y >> 8) << 2) | (j4.y & 3);
        int wz = ((j4.z >> 8) << 2) | (j4.z & 3);
        int ww = ((j4.w >> 8) << 2) | (j4.w & 3);
        int n = (int)((rw[wx] >> ((j4.x >> 2) & 63)) & 1ull)
              | ((int)((rw[wy] >> ((j4.y >> 2) & 63)) & 1ull) << 1)
              | ((int)((rw[wz] >> ((j4.z >> 2) & 63)) & 1ull) << 2)
              | ((int)((rw[ww] >> ((j4.w >> 2) & 63)) & 1ull) << 3);
        uint64_t b0 = __ballot(n & 1);
        uint64_t b1 = __ballot(n & 2);
        uint64_t b2 = __ballot(n & 4);
        uint64_t b3 = __ballot(n & 8);
        if ((lane >> 2) == it) {
            int e = lane & 3;
            v = (e == 0) ? b0 : (e == 1) ? b1 : (e == 2) ? b2 : b3;
        }
    }
    Rsel[(size_t)row * 64 + lane] = v;   // coalesced 512B per wave
}

// ------------- Kernel 4: new_g row r = OR of Rsel over nbr(idx[r]) ----------
__global__ __launch_bounds__(256) void k_newg(const uint64_t* __restrict__ R,
                                              const uint64_t* __restrict__ Rsel,
                                              const int* __restrict__ idx_i,
                                              float* __restrict__ out_g) {
    __shared__ __align__(16) uint16_t nbr[544];  // padded neighbor list
    __shared__ uint64_t T[4][64];                // per-wave partial ORs
    __shared__ uint64_t C[64];                   // combined row bitset

    int wave = threadIdx.x >> 6;
    int lane = threadIdx.x & 63;
    int r = blockIdx.x;
    int i = idx_i[r];

    // --- neighbor-list extraction (duplicated by all 4 waves; identical
    //     values -> benign concurrent LDS writes; own writes self-consistent)
    const ulonglong2* R2 = (const ulonglong2*)R;
    ulonglong2 own = R2[(size_t)i * 64 + lane];
    uint64_t m0 = own.x, m1 = own.y;
    int mycnt = __popcll(m0) + __popcll(m1);
    int incl = mycnt;
    #pragma unroll
    for (int d = 1; d < 64; d <<= 1) {
        int t = __shfl_up(incl, d);
        if (lane >= d) incl += t;
    }
    int pos = incl - mycnt;
    int total = __shfl(incl, 63);
    int w0 = lane * 2, w1 = lane * 2 + 1;
    while (m0) {
        int l = __builtin_ctzll(m0); m0 &= m0 - 1;
        nbr[pos++] = (uint16_t)(((w0 >> 2) << 8) + (l << 2) + (w0 & 3));
    }
    while (m1) {
        int l = __builtin_ctzll(m1); m1 &= m1 - 1;
        nbr[pos++] = (uint16_t)(((w1 >> 2) << 8) + (l << 2) + (w1 & 3));
    }
    int totalPad = (total + 7) & ~7;   // pad with entry 0 (OR idempotent)
    if (lane < totalPad - total) nbr[total + lane] = nbr[0];

    // --- phase 1: OR Rsel rows; each wave takes every 4th batch of 8
    uint64_t acc = 0;
    for (int n = wave * 8; n < totalPad; n += 32) {
        uint4 pk = *(const uint4*)&nbr[n];
        int k0 = pk.x & 0xffff, k1 = pk.x >> 16;
        int k2 = pk.y & 0xffff, k3 = pk.y >> 16;
        int k4 = pk.z & 0xffff, k5 = pk.z >> 16;
        int k6 = pk.w & 0xffff, k7 = pk.w >> 16;
        uint64_t v0 = Rsel[(size_t)k0 * 64 + lane];
        uint64_t v1 = Rsel[(size_t)k1 * 64 + lane];
        uint64_t v2 = Rsel[(size_t)k2 * 64 + lane];
        uint64_t v3 = Rsel[(size_t)k3 * 64 + lane];
        uint64_t v4 = Rsel[(size_t)k4 * 64 + lane];
        uint64_t v5 = Rsel[(size_t)k5 * 64 + lane];
        uint64_t v6 = Rsel[(size_t)k6 * 64 + lane];
        uint64_t v7 = Rsel[(size_t)k7 * 64 + lane];
        acc |= ((v0 | v1) | (v2 | v3)) | ((v4 | v5) | (v6 | v7));
    }
    T[wave][lane] = acc;
    __syncthreads();

    uint64_t comb = T[0][lane] | T[1][lane] | T[2][lane] | T[3][lane];
    C[lane] = comb;   // every wave writes all 64 words (identical values)
    int cnt = __popcll(comb);
    #pragma unroll
    for (int off = 32; off >= 1; off >>= 1) cnt += __shfl_xor(cnt, off);
    float recip = 1.0f / (float)cnt;   // bit * recip == exact 1/rowsum

    // --- phase 2: wave writes its 4 of the 16 column-iterations
    f32x4* dst = (f32x4*)(out_g + (size_t)r * KSEL);
    #pragma unroll
    for (int s = 0; s < 4; ++s) {
        int it = wave * 4 + s;
        uint64_t wA = C[it * 4 + 0], wB = C[it * 4 + 1];
        uint64_t wC = C[it * 4 + 2], wD = C[it * 4 + 3];
        f32x4 v;
        v.x = ((wA >> lane) & 1ull) ? recip : 0.0f;
        v.y = ((wB >> lane) & 1ull) ? recip : 0.0f;
        v.z = ((wC >> lane) & 1ull) ? recip : 0.0f;
        v.w = ((wD >> lane) & 1ull) ? recip : 0.0f;
        __builtin_nontemporal_store(v, &dst[it * 64 + lane]);
    }
}

extern "C" void kernel_launch(void* const* d_in, const int* in_sizes, int n_in,
                              void* d_out, int out_size, void* d_ws, size_t ws_size,
                              hipStream_t stream) {
    const float* g = (const float*)d_in[0];
    const float* h = (const float*)d_in[1];
    const float* W = (const float*)d_in[2];
    const float* b = (const float*)d_in[3];

    float* out_g   = (float*)d_out;                // K*K
    float* out_h   = out_g + (size_t)KSEL * KSEL;  // K*D
    float* out_idx = out_h + (size_t)KSEL * DD;    // K

    char* ws = (char*)d_ws;
    double*   w64    = (double*)ws;                          // 64 KB
    float*    val    = (float*)(ws + 65536);                 // 32 KB
    int*      idx_i  = (int*)(ws + 98304);                   // 16 KB
    uint64_t* R      = (uint64_t*)(ws + 131072);             // 8 MB
    uint64_t* Rsel   = (uint64_t*)(ws + 131072 + 8388608);   // 4 MB

    k_pack_scores<<<4096, 256, 0, stream>>>(g, h, W, b, R, w64, val);
    k_topk<<<NN / 16, 1024, 0, stream>>>(w64, val, h, idx_i, out_idx, out_h);
    k_sel<<<NN / 8, 512, 0, stream>>>(R, idx_i, Rsel);
    k_newg<<<KSEL, 256, 0, stream>>>(R, Rsel, idx_i, out_g);
}